// Round 7
// baseline (421.716 us; speedup 1.0000x reference)
//
#include <hip/hip_runtime.h>
#include <math.h>

#define D_MODEL 1024
#define SEQ 2048
#define NTOK 4096

typedef __attribute__((ext_vector_type(8))) short bf16x8;
typedef __attribute__((ext_vector_type(4))) float f32x4;

__device__ __forceinline__ unsigned short f2bf(float f) {
    union { float f; unsigned u; } v; v.f = f;
    unsigned r = v.u + 0x7FFFu + ((v.u >> 16) & 1u);   // RNE
    return (unsigned short)(r >> 16);
}
__device__ __forceinline__ float bf2f(unsigned short u) {
    union { unsigned u; float f; } v; v.u = ((unsigned)u) << 16; return v.f;
}
// pack two fp32 -> (bf16(y)<<16)|bf16(x), round-to-nearest (ties up)
__device__ __forceinline__ unsigned pk2bf(float x, float y) {
    union { float f; unsigned u; } a, b;
    a.f = x; b.f = y;
    return ((b.u + 0x8000u) & 0xFFFF0000u) | ((a.u + 0x8000u) >> 16);
}

// async global->LDS, 16B per lane. LDS dest must be wave-uniform base + lane*16.
__device__ __forceinline__ void ld_g2l(const void* g, void* l) {
    __builtin_amdgcn_global_load_lds(
        (const __attribute__((address_space(1))) void*)g,
        (__attribute__((address_space(3))) void*)l, 16, 0, 0);
}

// ---------------------------------------------------------------------------
// prep_weights: ONE dispatch does all 6 fp32[K,N]->bf16[N,K] transposes
// plus silu(cond)->bf16.
// ---------------------------------------------------------------------------
__global__ __launch_bounds__(256) void prep_weights(
    const float* __restrict__ p1, const float* __restrict__ p2,
    const float* __restrict__ qkvw, const float* __restrict__ attnw,
    const float* __restrict__ f1, const float* __restrict__ f2,
    const float* __restrict__ cond,
    unsigned short* __restrict__ wt_cond, unsigned short* __restrict__ wt_qkv,
    unsigned short* __restrict__ wt_attn, unsigned short* __restrict__ wt_ffn1,
    unsigned short* __restrict__ wt_ffn2, unsigned short* __restrict__ siluc)
{
    const int t = blockIdx.x;
    if (t >= 3584) {   // silu path: 512 blocks x 1024 float4
        const int base = (t - 3584) * 1024 + threadIdx.x;
#pragma unroll
        for (int i = 0; i < 4; i++) {
            const int idx = base + i * 256;
            float4 v = ((const float4*)cond)[idx];
            ushort4 o;
            o.x = f2bf(v.x / (1.f + expf(-v.x)));
            o.y = f2bf(v.y / (1.f + expf(-v.y)));
            o.z = f2bf(v.z / (1.f + expf(-v.z)));
            o.w = f2bf(v.w / (1.f + expf(-v.w)));
            ((ushort4*)siluc)[idx] = o;
        }
        return;
    }
    const float* src; unsigned short* dst; int K, N, lt;
    if (t < 512)       { src = (t < 256) ? p1 : p2;
                         dst = wt_cond + (t < 256 ? 0 : 2048 * 512);
                         K = 512;  N = 2048; lt = t & 255; }
    else if (t < 1280) { src = qkvw;  dst = wt_qkv;  K = 1024; N = 3072; lt = t - 512; }
    else if (t < 1536) { src = attnw; dst = wt_attn; K = 1024; N = 1024; lt = t - 1280; }
    else if (t < 2560) { src = f1;    dst = wt_ffn1; K = 1024; N = 4096; lt = t - 1536; }
    else               { src = f2;    dst = wt_ffn2; K = 4096; N = 1024; lt = t - 2560; }
    const int ntile = N >> 6;
    const int n0 = (lt % ntile) * 64, k0 = (lt / ntile) * 64;

    __shared__ float tile[64][65];
    const int tx = threadIdx.x & 15, ty = threadIdx.x >> 4;
#pragma unroll
    for (int i = 0; i < 4; i++) {
        const int k = ty + i * 16;
        float4 v = *(const float4*)&src[(size_t)(k0 + k) * N + n0 + tx * 4];
        tile[k][tx * 4 + 0] = v.x; tile[k][tx * 4 + 1] = v.y;
        tile[k][tx * 4 + 2] = v.z; tile[k][tx * 4 + 3] = v.w;
    }
    __syncthreads();
#pragma unroll
    for (int i = 0; i < 4; i++) {
        const int n = ty + i * 16;
        ushort4 o;
        o.x = f2bf(tile[tx * 4 + 0][n]); o.y = f2bf(tile[tx * 4 + 1][n]);
        o.z = f2bf(tile[tx * 4 + 2][n]); o.w = f2bf(tile[tx * 4 + 3][n]);
        *(ushort4*)&dst[(size_t)(n0 + n) * K + k0 + tx * 4] = o;
    }
}

// ---------------------------------------------------------------------------
// bf16 MFMA GEMM: C = epi(A[M,K] @ Bt[N,K]^T). BM x 128 tile, BK=64,
// 4 waves (2x2), 16x16x32 MFMA, global_load_lds staging, XOR swizzle.
// ---------------------------------------------------------------------------
#define EPI_GB   0
#define EPI_QKV  1
#define EPI_PROJ 2
#define EPI_FFN1 3
#define EPI_FFN2 4

template<int EPI, int BM>
__global__ __launch_bounds__(256) void gemm_bf16(
    const unsigned short* __restrict__ A,
    const unsigned short* __restrict__ Bt,
    const float* __restrict__ bias, const float* __restrict__ bias2,
    const float* __restrict__ res,
    void* __restrict__ Cv,
    unsigned short* __restrict__ qb, unsigned short* __restrict__ kb,
    unsigned short* __restrict__ vtb,
    int K)
{
    constexpr int WM = BM / 2;     // 64 or 32
    constexpr int MT = WM / 16;    // 4 or 2
    __shared__ __align__(16) unsigned short As[BM * 64];
    __shared__ __align__(16) unsigned short Bs[128 * 64];
    const int tid = threadIdx.x;
    const int lane = tid & 63, w = tid >> 6;
    const int cc = lane & 15, quad = lane >> 4;
    const int wm = (w >> 1) * WM, wn = (w & 1) * 64;
    const int m0 = blockIdx.y * BM, n0 = blockIdx.x * 128;

    f32x4 acc[MT][4];
#pragma unroll
    for (int i = 0; i < MT; i++)
#pragma unroll
        for (int j = 0; j < 4; j++) acc[i][j] = (f32x4)0.f;

    for (int k0 = 0; k0 < K; k0 += 64) {
        __syncthreads();
#pragma unroll
        for (int i = 0; i < BM / 32; i++) {
            const int idx = i * 256 + tid;
            const int row = idx >> 3, c = idx & 7;
            const int kc = (c ^ (row & 7)) << 3;
            ld_g2l(&A[(size_t)(m0 + row) * K + k0 + kc], &As[idx << 3]);
        }
#pragma unroll
        for (int i = 0; i < 4; i++) {
            const int idx = i * 256 + tid;
            const int row = idx >> 3, c = idx & 7;
            const int kc = (c ^ (row & 7)) << 3;
            ld_g2l(&Bt[(size_t)(n0 + row) * K + k0 + kc], &Bs[idx << 3]);
        }
        __syncthreads();
#pragma unroll
        for (int ks = 0; ks < 2; ks++) {
            bf16x8 af[MT], bfr[4];
            const int pc = (((ks << 2) | quad) ^ (cc & 7)) << 3;
#pragma unroll
            for (int t = 0; t < MT; t++)
                af[t]  = *(const bf16x8*)&As[(wm + t * 16 + cc) * 64 + pc];
#pragma unroll
            for (int t = 0; t < 4; t++)
                bfr[t] = *(const bf16x8*)&Bs[(wn + t * 16 + cc) * 64 + pc];
#pragma unroll
            for (int mt = 0; mt < MT; mt++)
#pragma unroll
                for (int nt = 0; nt < 4; nt++)
                    acc[mt][nt] = __builtin_amdgcn_mfma_f32_16x16x32_bf16(
                        af[mt], bfr[nt], acc[mt][nt], 0, 0, 0);
        }
    }

    // ---- epilogues. C-frag: row = quad*4+r, col = cc ----
    if (EPI == EPI_GB) {
        unsigned short* C = (unsigned short*)Cv;
#pragma unroll
        for (int mt = 0; mt < MT; mt++)
#pragma unroll
        for (int r = 0; r < 4; r++) {
            const int m = m0 + wm + mt * 16 + quad * 4 + r;
#pragma unroll
            for (int nt = 0; nt < 4; nt++) {
                const int n = n0 + wn + nt * 16 + cc;
                const float b = (n < 2048) ? bias[n] : bias2[n - 2048];
                C[(size_t)m * 4096 + n] = f2bf(acc[mt][nt][r] + b);
            }
        }
    } else if (EPI == EPI_PROJ) {
        float* C = (float*)Cv;
#pragma unroll
        for (int mt = 0; mt < MT; mt++)
#pragma unroll
        for (int r = 0; r < 4; r++) {
            const int m = m0 + wm + mt * 16 + quad * 4 + r;
#pragma unroll
            for (int nt = 0; nt < 4; nt++) {
                const int n = n0 + wn + nt * 16 + cc;
                C[(size_t)m * 1024 + n] = acc[mt][nt][r] + res[(size_t)m * 1024 + n];
            }
        }
    } else if (EPI == EPI_FFN1) {
        unsigned short* C = (unsigned short*)Cv;
#pragma unroll
        for (int mt = 0; mt < MT; mt++)
#pragma unroll
        for (int r = 0; r < 4; r++) {
            const int m = m0 + wm + mt * 16 + quad * 4 + r;
#pragma unroll
            for (int nt = 0; nt < 4; nt++) {
                const int n = n0 + wn + nt * 16 + cc;
                float v = acc[mt][nt][r] + bias[n];
                // tanh-approx GELU via sigmoid identity:
                // gelu(x) ~= x * sigmoid(1.5957691*(x+0.044715x^3))*2 ... i.e.
                // x / (1 + exp2(-2.3022084*(x + 0.044715 x^3)))
                const float u = v + 0.044715f * v * v * v;
                const float g = v / (1.f + exp2f(-2.3022084f * u));
                C[(size_t)m * 4096 + n] = f2bf(g);
            }
        }
    } else if (EPI == EPI_FFN2) {
        float* C = (float*)Cv;
#pragma unroll
        for (int mt = 0; mt < MT; mt++)
#pragma unroll
        for (int r = 0; r < 4; r++) {
            const int m = m0 + wm + mt * 16 + quad * 4 + r;
#pragma unroll
            for (int nt = 0; nt < 4; nt++) {
                const int n = n0 + wn + nt * 16 + cc;
                C[(size_t)m * 1024 + n] = acc[mt][nt][r] + bias[n] + res[(size_t)m * 1024 + n];
            }
        }
    } else {  // EPI_QKV: N=3072, split q/k bf16 + PERMUTED v^T bf16
        const int region = n0 >> 10;
        const int b = m0 >> 11;
        if (region < 2) {
            unsigned short* dst = region ? kb : qb;
            // Q prescale folds softmax 1/sqrt(d) AND log2(e) (exp2-domain softmax)
            const float sc = region ? 1.0f : 0.125f * 1.44269504088896340736f;
#pragma unroll
            for (int mt = 0; mt < MT; mt++)
#pragma unroll
            for (int r = 0; r < 4; r++) {
                const int m = m0 + wm + mt * 16 + quad * 4 + r;
                const int s = m & 2047;
#pragma unroll
                for (int nt = 0; nt < 4; nt++) {
                    const int n = (n0 + wn + nt * 16 + cc) & 1023;
                    const int hh = n >> 6, d = n & 63;
                    dst[(((size_t)b * 16 + hh) * 2048 + s) * 64 + d] =
                        f2bf(acc[mt][nt][r] * sc);
                }
            }
        } else {
            // V^T stored pre-permuted into PV B-fragment key order
            const int sb = (m0 + wm) & 2047;
#pragma unroll
            for (int mt = 0; mt < MT; mt++) {
                const int kpos = sb + ((mt >> 1) << 5) + (quad << 3) + ((mt & 1) << 2);
#pragma unroll
                for (int nt = 0; nt < 4; nt++) {
                    const int n = (n0 + wn + nt * 16 + cc) & 1023;
                    const int hh = n >> 6, d = n & 63;
                    ushort4 o;
                    o.x = f2bf(acc[mt][nt][0]); o.y = f2bf(acc[mt][nt][1]);
                    o.z = f2bf(acc[mt][nt][2]); o.w = f2bf(acc[mt][nt][3]);
                    *(ushort4*)&vtb[(((size_t)b * 16 + hh) * 64 + d) * 2048 + kpos] = o;
                }
            }
        }
    }
}

// ---------------------------------------------------------------------------
// Transposed MFMA flash attention v5: 8 waves x 32 q = 256-q tile,
// split-K over keys (z in {0,1}), 128-key staged chunks (32KB LDS, half the
// barriers of v4), static-max exp2 softmax, partial O/l out (bf16/f32).
// grid (SEQ/256, B*H, 2) = 512 blocks x 8 waves -> 16 waves/CU.
// ---------------------------------------------------------------------------
__global__ __launch_bounds__(512) void attn_mfma(
    const unsigned short* __restrict__ qb, const unsigned short* __restrict__ kb,
    const unsigned short* __restrict__ vtb,
    unsigned short* __restrict__ Op0, unsigned short* __restrict__ Op1,
    float* __restrict__ lp)
{
    __shared__ __align__(16) unsigned short ks[128 * 64];   // [key][d] swizzled
    __shared__ __align__(16) unsigned short vts[64 * 128];  // [d][pos] swizzled

    const int tid = threadIdx.x;
    const int lane = tid & 63, w = tid >> 6;           // 8 waves
    const int c = lane & 15, quad = lane >> 4;
    const int bh = blockIdx.y;
    const int q0 = blockIdx.x * 256;
    const int z = blockIdx.z;
    const int kk0 = z * 1024;

    // Q as B-operand: lane needs Q[q0+w*32+qs*16+c][kh*32+quad*8+j]
    bf16x8 qf[2][2];   // [qs][kh]
#pragma unroll
    for (int qs = 0; qs < 2; qs++) {
        const size_t base = (((size_t)bh * 2048) + q0 + w * 32 + qs * 16 + c) * 64 + quad * 8;
        qf[qs][0] = *(const bf16x8*)&qb[base];
        qf[qs][1] = *(const bf16x8*)&qb[base + 32];
    }

    f32x4 of[2][4];
#pragma unroll
    for (int qs = 0; qs < 2; qs++)
#pragma unroll
        for (int i = 0; i < 4; i++) of[qs][i] = (f32x4)0.f;
    float l[2] = {0.f, 0.f};

    const size_t kbase = ((size_t)bh * 2048) * 64;
    const size_t vbase = ((size_t)bh * 64) * 2048;

    for (int kk = kk0; kk < kk0 + 1024; kk += 128) {
        __syncthreads();
        // K: [128 key][64 d], 1024 16B-chunks, 8 chunks/row, xor-swizzled
#pragma unroll
        for (int i = 0; i < 2; i++) {
            const int idx = i * 512 + tid;
            const int row = idx >> 3, pc = idx & 7;
            const int lc = pc ^ (row & 7);
            ld_g2l(&kb[kbase + (size_t)(kk + row) * 64 + lc * 8], &ks[idx << 3]);
        }
        // V^T: [64 d][128 pos], 16 chunks/row, swizzle low 3 bits only
#pragma unroll
        for (int i = 0; i < 2; i++) {
            const int idx = i * 512 + tid;
            const int row = idx >> 4, pc = idx & 15;
            const int lc = (pc & 8) | ((pc & 7) ^ (row & 7));
            ld_g2l(&vtb[vbase + (size_t)row * 2048 + kk + lc * 8], &vts[idx << 3]);
        }
        __syncthreads();

#pragma unroll
        for (int hf2 = 0; hf2 < 2; hf2++) {   // two 64-key halves, no barrier
            // ---- S^T = K @ Q^T ----
            f32x4 sc[2][4];
#pragma unroll
            for (int qs = 0; qs < 2; qs++)
#pragma unroll
                for (int t = 0; t < 4; t++) sc[qs][t] = (f32x4)0.f;
#pragma unroll
            for (int t = 0; t < 4; t++) {
#pragma unroll
                for (int kh = 0; kh < 2; kh++) {
                    const int phys = ((kh * 4 + quad) ^ (c & 7)) << 3;
                    bf16x8 kf = *(const bf16x8*)&ks[(hf2 * 64 + t * 16 + c) * 64 + phys];
#pragma unroll
                    for (int qs = 0; qs < 2; qs++)
                        sc[qs][t] = __builtin_amdgcn_mfma_f32_16x16x32_bf16(
                            kf, qf[qs][kh], sc[qs][t], 0, 0, 0);
                }
            }

            // ---- softmax: static max, exp2 domain, lane-local l ----
            bf16x8 pb[2][2];
#pragma unroll
            for (int qs = 0; qs < 2; qs++) {
#pragma unroll
                for (int t = 0; t < 4; t++)
#pragma unroll
                    for (int r = 0; r < 4; r++) {
                        const float p = exp2f(sc[qs][t][r]);
                        sc[qs][t][r] = p;
                        l[qs] += p;
                    }
#pragma unroll
                for (int kh = 0; kh < 2; kh++) {
                    union { int4 i; bf16x8 v; } u;
                    u.i.x = pk2bf(sc[qs][2 * kh][0],     sc[qs][2 * kh][1]);
                    u.i.y = pk2bf(sc[qs][2 * kh][2],     sc[qs][2 * kh][3]);
                    u.i.z = pk2bf(sc[qs][2 * kh + 1][0], sc[qs][2 * kh + 1][1]);
                    u.i.w = pk2bf(sc[qs][2 * kh + 1][2], sc[qs][2 * kh + 1][3]);
                    pb[qs][kh] = u.v;
                }
            }

            // ---- O^T += V^T @ P^T ----
#pragma unroll
            for (int dt = 0; dt < 4; dt++) {
#pragma unroll
                for (int kh = 0; kh < 2; kh++) {
                    const int phys = ((hf2 * 8) | ((kh * 4 + quad) ^ (c & 7))) << 3;
                    bf16x8 vf = *(const bf16x8*)&vts[(dt * 16 + c) * 128 + phys];
#pragma unroll
                    for (int qs = 0; qs < 2; qs++)
                        of[qs][dt] = __builtin_amdgcn_mfma_f32_16x16x32_bf16(
                            vf, pb[qs][kh], of[qs][dt], 0, 0, 0);
                }
            }
        }
    }

    // ---- epilogue: store UNSCALED partial O (bf16) + partial l ----
    unsigned short* Op = z ? Op1 : Op0;
    const int b = bh >> 4, hh = bh & 15;
#pragma unroll
    for (int qs = 0; qs < 2; qs++) {
        float lq = l[qs];
        lq += __shfl_xor(lq, 16, 64);
        lq += __shfl_xor(lq, 32, 64);
        const int q = q0 + w * 32 + qs * 16 + c;
        if (lane < 16)
            lp[((size_t)z * 32 + bh) * 2048 + q] = lq;
        const size_t row = (size_t)(b * 2048 + q);
#pragma unroll
        for (int dt = 0; dt < 4; dt++) {
            ushort4 o;
            o.x = f2bf(of[qs][dt][0]); o.y = f2bf(of[qs][dt][1]);
            o.z = f2bf(of[qs][dt][2]); o.w = f2bf(of[qs][dt][3]);
            *(ushort4*)&Op[row * 1024 + hh * 64 + dt * 16 + quad * 4] = o;
        }
    }
}

// ---------------------------------------------------------------------------
// merge_attn: attnb = (Op0 + Op1) / (l0 + l1), bf16 out. One block per token.
// ---------------------------------------------------------------------------
__global__ __launch_bounds__(256) void merge_attn(
    const unsigned short* __restrict__ Op0, const unsigned short* __restrict__ Op1,
    const float* __restrict__ lp, unsigned short* __restrict__ attnb)
{
    const int row = blockIdx.x;
    const int b = row >> 11, s = row & 2047;
    const int tid = threadIdx.x;
    const int n = tid * 4, h = tid >> 4;
    const float l0 = lp[((size_t)b * 16 + h) * 2048 + s];
    const float l1 = lp[((size_t)32 + b * 16 + h) * 2048 + s];
    const float inv = 1.f / (l0 + l1);
    const size_t off = (size_t)row * 1024 + n;
    ushort4 a = *(const ushort4*)&Op0[off];
    ushort4 bb = *(const ushort4*)&Op1[off];
    ushort4 o;
    o.x = f2bf((bf2f(a.x) + bf2f(bb.x)) * inv);
    o.y = f2bf((bf2f(a.y) + bf2f(bb.y)) * inv);
    o.z = f2bf((bf2f(a.z) + bf2f(bb.z)) * inv);
    o.w = f2bf((bf2f(a.w) + bf2f(bb.w)) * inv);
    *(ushort4*)&attnb[off] = o;
}

// ---------------------------------------------------------------------------
// AdaLN (vectorized): x fp32, gamma/beta bf16 (stride 4096, +gboff), out bf16
// ---------------------------------------------------------------------------
__global__ __launch_bounds__(256) void adaln_bf(
    const float* __restrict__ x, const unsigned short* __restrict__ gb, int gboff,
    unsigned short* __restrict__ h)
{
    const int row = blockIdx.x;
    const float* xr = x + (size_t)row * D_MODEL;
    float4 v = ((const float4*)xr)[threadIdx.x];
    float s = v.x + v.y + v.z + v.w;
    float ss = v.x * v.x + v.y * v.y + v.z * v.z + v.w * v.w;
#pragma unroll
    for (int off = 1; off < 64; off <<= 1) {
        s  += __shfl_xor(s, off, 64);
        ss += __shfl_xor(ss, off, 64);
    }
    __shared__ float red[8];
    const int wave = threadIdx.x >> 6;
    if ((threadIdx.x & 63) == 0) { red[wave] = s; red[4 + wave] = ss; }
    __syncthreads();
    s  = red[0] + red[1] + red[2] + red[3];
    ss = red[4] + red[5] + red[6] + red[7];
    const float mu = s * (1.f / 1024.f);
    const float var = ss * (1.f / 1024.f) - mu * mu;
    const float rstd = rsqrtf(var + 1e-5f);
    const int c = threadIdx.x * 4;
    ushort4 g4 = *(const ushort4*)&gb[(size_t)row * 4096 + gboff + c];
    ushort4 b4 = *(const ushort4*)&gb[(size_t)row * 4096 + gboff + 1024 + c];
    ushort4 o;
    o.x = f2bf((v.x - mu) * rstd * (1.f + bf2f(g4.x)) + bf2f(b4.x));
    o.y = f2bf((v.y - mu) * rstd * (1.f + bf2f(g4.y)) + bf2f(b4.y));
    o.z = f2bf((v.z - mu) * rstd * (1.f + bf2f(g4.z)) + bf2f(b4.z));
    o.w = f2bf((v.w - mu) * rstd * (1.f + bf2f(g4.w)) + bf2f(b4.w));
    *(ushort4*)&h[(size_t)row * 1024 + c] = o;
}

// ---------------------------------------------------------------------------
extern "C" void kernel_launch(void* const* d_in, const int* in_sizes, int n_in,
                              void* d_out, int out_size, void* d_ws, size_t ws_size,
                              hipStream_t stream)
{
    const float* x      = (const float*)d_in[0];
    const float* cond   = (const float*)d_in[1];
    const float* p1_w   = (const float*)d_in[2];
    const float* p1_b   = (const float*)d_in[3];
    const float* qkv_w  = (const float*)d_in[4];
    const float* attn_w = (const float*)d_in[5];
    const float* p2_w   = (const float*)d_in[6];
    const float* p2_b   = (const float*)d_in[7];
    const float* ffn_w1 = (const float*)d_in[8];
    const float* ffn_b1 = (const float*)d_in[9];
    const float* ffn_w2 = (const float*)d_in[10];
    const float* ffn_b2 = (const float*)d_in[11];
    float* out = (float*)d_out;

    char* ws = (char*)d_ws;
    const size_t MB = 1024ull * 1024ull;
    unsigned short* wt_cond = (unsigned short*)(ws);             // [0,4)   dead after GB
    unsigned short* wt_qkv  = (unsigned short*)(ws + 4 * MB);    // [4,10)  dead after QKV
    unsigned short* wt_attn = (unsigned short*)(ws + 10 * MB);   // [10,12)
    unsigned short* wt_ffn1 = (unsigned short*)(ws + 12 * MB);   // [12,20)
    unsigned short* wt_ffn2 = (unsigned short*)(ws + 20 * MB);   // [20,28)
    unsigned short* siluc   = (unsigned short*)(ws + 28 * MB);   // [28,32) dead after GB
    unsigned short* gb      = (unsigned short*)(ws + 32 * MB);   // [32,64)
    unsigned short* h       = (unsigned short*)(ws + 64 * MB);   // [64,72) h1 dead after QKV
    float*          x1      = (float*)(ws + 72 * MB);            // [72,88)
    unsigned short* qb      = (unsigned short*)(ws + 88 * MB);   // [88,96)
    unsigned short* kb      = (unsigned short*)(ws + 96 * MB);   // [96,104)
    unsigned short* vtb     = (unsigned short*)(ws + 104 * MB);  // [104,112)
    unsigned short* attnb   = (unsigned short*)(ws + 112 * MB);  // [112,120)
    unsigned short* ff1     = (unsigned short*)(ws + 88 * MB);   // [88,120) overlay
    // attention partials, overlaying regions dead by attention time:
    unsigned short* Op0     = (unsigned short*)(ws);             // [0,8)
    unsigned short* Op1     = (unsigned short*)(ws + 64 * MB);   // [64,72)
    float*          lp      = (float*)(ws + 28 * MB);            // [28,28.5)

    dim3 blk(256);

    // one dispatch: all weight transposes + silu(cond)
    prep_weights<<<dim3(4096), blk, 0, stream>>>(
        p1_w, p2_w, qkv_w, attn_w, ffn_w1, ffn_w2, cond,
        wt_cond, wt_qkv, wt_attn, wt_ffn1, wt_ffn2, siluc);

    // gb = silu(cond) @ [p1_w|p2_w] + [p1_b|p2_b]   (4096x4096, K=512)
    gemm_bf16<EPI_GB, 128><<<dim3(32, 32), blk, 0, stream>>>(
        siluc, wt_cond, p1_b, p2_b, nullptr, gb, nullptr, nullptr, nullptr, 512);
    // h1 = adaln(x, gb1)
    adaln_bf<<<NTOK, blk, 0, stream>>>(x, gb, 0, h);
    // qkv = h1 @ qkv_w  -> q/k bf16 (Q prescaled), v^T bf16 pre-permuted
    gemm_bf16<EPI_QKV, 128><<<dim3(24, 32), blk, 0, stream>>>(
        h, wt_qkv, nullptr, nullptr, nullptr, nullptr, qb, kb, vtb, 1024);
    // attention: split-K over keys, 8-wave blocks, 128-key staged chunks
    attn_mfma<<<dim3(SEQ / 256, 32, 2), dim3(512), 0, stream>>>(
        qb, kb, vtb, Op0, Op1, lp);
    merge_attn<<<dim3(NTOK), blk, 0, stream>>>(Op0, Op1, lp, attnb);
    // x1 = x + attn @ attn_out_w   (BM=64 -> 512 blocks)
    gemm_bf16<EPI_PROJ, 64><<<dim3(8, 64), blk, 0, stream>>>(
        attnb, wt_attn, nullptr, nullptr, x, x1, nullptr, nullptr, nullptr, 1024);
    // h2 = adaln(x1, gb2)
    adaln_bf<<<NTOK, blk, 0, stream>>>(x1, gb, 2048, h);
    // ff1 = gelu_tanh(h2 @ ffn_w1 + b1)
    gemm_bf16<EPI_FFN1, 128><<<dim3(32, 32), blk, 0, stream>>>(
        h, wt_ffn1, ffn_b1, nullptr, nullptr, ff1, nullptr, nullptr, nullptr, 1024);
    // out = x1 + ff1 @ ffn_w2 + b2   (BM=64 -> 512 blocks)
    gemm_bf16<EPI_FFN2, 64><<<dim3(8, 64), blk, 0, stream>>>(
        ff1, wt_ffn2, ffn_b2, nullptr, x1, out, nullptr, nullptr, nullptr, 4096);
}

// Round 8
// 410.746 us; speedup vs baseline: 1.0267x; 1.0267x over previous
//
#include <hip/hip_runtime.h>
#include <math.h>

#define D_MODEL 1024
#define SEQ 2048
#define NTOK 4096

typedef __attribute__((ext_vector_type(8))) short bf16x8;
typedef __attribute__((ext_vector_type(4))) float f32x4;

__device__ __forceinline__ unsigned short f2bf(float f) {
    union { float f; unsigned u; } v; v.f = f;
    unsigned r = v.u + 0x7FFFu + ((v.u >> 16) & 1u);   // RNE
    return (unsigned short)(r >> 16);
}
__device__ __forceinline__ float bf2f(unsigned short u) {
    union { unsigned u; float f; } v; v.u = ((unsigned)u) << 16; return v.f;
}
// pack two fp32 -> (bf16(y)<<16)|bf16(x)
__device__ __forceinline__ unsigned pk2bf(float x, float y) {
    union { float f; unsigned u; } a, b;
    a.f = x; b.f = y;
    return ((b.u + 0x8000u) & 0xFFFF0000u) | ((a.u + 0x8000u) >> 16);
}

// async global->LDS, 16B per lane. LDS dest must be wave-uniform base + lane*16.
__device__ __forceinline__ void ld_g2l(const void* g, void* l) {
    __builtin_amdgcn_global_load_lds(
        (const __attribute__((address_space(1))) void*)g,
        (__attribute__((address_space(3))) void*)l, 16, 0, 0);
}

// ---------------------------------------------------------------------------
// prep_weights: ONE dispatch does all 6 fp32[K,N]->bf16[N,K] transposes
// plus silu(cond)->bf16.
// ---------------------------------------------------------------------------
__global__ __launch_bounds__(256) void prep_weights(
    const float* __restrict__ p1, const float* __restrict__ p2,
    const float* __restrict__ qkvw, const float* __restrict__ attnw,
    const float* __restrict__ f1, const float* __restrict__ f2,
    const float* __restrict__ cond,
    unsigned short* __restrict__ wt_cond, unsigned short* __restrict__ wt_qkv,
    unsigned short* __restrict__ wt_attn, unsigned short* __restrict__ wt_ffn1,
    unsigned short* __restrict__ wt_ffn2, unsigned short* __restrict__ siluc)
{
    const int t = blockIdx.x;
    if (t >= 3584) {   // silu path: 512 blocks x 1024 float4
        const int base = (t - 3584) * 1024 + threadIdx.x;
#pragma unroll
        for (int i = 0; i < 4; i++) {
            const int idx = base + i * 256;
            float4 v = ((const float4*)cond)[idx];
            ushort4 o;
            o.x = f2bf(v.x / (1.f + expf(-v.x)));
            o.y = f2bf(v.y / (1.f + expf(-v.y)));
            o.z = f2bf(v.z / (1.f + expf(-v.z)));
            o.w = f2bf(v.w / (1.f + expf(-v.w)));
            ((ushort4*)siluc)[idx] = o;
        }
        return;
    }
    const float* src; unsigned short* dst; int K, N, lt;
    if (t < 512)       { src = (t < 256) ? p1 : p2;
                         dst = wt_cond + (t < 256 ? 0 : 2048 * 512);
                         K = 512;  N = 2048; lt = t & 255; }
    else if (t < 1280) { src = qkvw;  dst = wt_qkv;  K = 1024; N = 3072; lt = t - 512; }
    else if (t < 1536) { src = attnw; dst = wt_attn; K = 1024; N = 1024; lt = t - 1280; }
    else if (t < 2560) { src = f1;    dst = wt_ffn1; K = 1024; N = 4096; lt = t - 1536; }
    else               { src = f2;    dst = wt_ffn2; K = 4096; N = 1024; lt = t - 2560; }
    const int ntile = N >> 6;
    const int n0 = (lt % ntile) * 64, k0 = (lt / ntile) * 64;

    __shared__ float tile[64][65];
    const int tx = threadIdx.x & 15, ty = threadIdx.x >> 4;
#pragma unroll
    for (int i = 0; i < 4; i++) {
        const int k = ty + i * 16;
        float4 v = *(const float4*)&src[(size_t)(k0 + k) * N + n0 + tx * 4];
        tile[k][tx * 4 + 0] = v.x; tile[k][tx * 4 + 1] = v.y;
        tile[k][tx * 4 + 2] = v.z; tile[k][tx * 4 + 3] = v.w;
    }
    __syncthreads();
#pragma unroll
    for (int i = 0; i < 4; i++) {
        const int n = ty + i * 16;
        ushort4 o;
        o.x = f2bf(tile[tx * 4 + 0][n]); o.y = f2bf(tile[tx * 4 + 1][n]);
        o.z = f2bf(tile[tx * 4 + 2][n]); o.w = f2bf(tile[tx * 4 + 3][n]);
        *(ushort4*)&dst[(size_t)(n0 + n) * K + k0 + tx * 4] = o;
    }
}

// ---------------------------------------------------------------------------
// bf16 MFMA GEMM: C = epi(A[M,K] @ Bt[N,K]^T). BM x 128 tile, BK=64,
// 4 waves (2x2), 16x16x32 MFMA, global_load_lds staging, XOR swizzle.
// __launch_bounds__(256,4): cap unified VGPR+AGPR at 128/wave -> 4 waves/SIMD.
// ---------------------------------------------------------------------------
#define EPI_GB   0
#define EPI_QKV  1
#define EPI_PROJ 2
#define EPI_FFN1 3
#define EPI_FFN2 4

template<int EPI, int BM>
__global__ __launch_bounds__(256, 4) void gemm_bf16(
    const unsigned short* __restrict__ A,
    const unsigned short* __restrict__ Bt,
    const float* __restrict__ bias, const float* __restrict__ bias2,
    const float* __restrict__ res,
    void* __restrict__ Cv,
    unsigned short* __restrict__ qb, unsigned short* __restrict__ kb,
    unsigned short* __restrict__ vtb,
    int K)
{
    constexpr int WM = BM / 2;     // 64 or 32
    constexpr int MT = WM / 16;    // 4 or 2
    __shared__ __align__(16) unsigned short As[BM * 64];
    __shared__ __align__(16) unsigned short Bs[128 * 64];
    const int tid = threadIdx.x;
    const int lane = tid & 63, w = tid >> 6;
    const int cc = lane & 15, quad = lane >> 4;
    const int wm = (w >> 1) * WM, wn = (w & 1) * 64;
    const int m0 = blockIdx.y * BM, n0 = blockIdx.x * 128;

    f32x4 acc[MT][4];
#pragma unroll
    for (int i = 0; i < MT; i++)
#pragma unroll
        for (int j = 0; j < 4; j++) acc[i][j] = (f32x4)0.f;

    for (int k0 = 0; k0 < K; k0 += 64) {
        __syncthreads();
#pragma unroll
        for (int i = 0; i < BM / 32; i++) {
            const int idx = i * 256 + tid;
            const int row = idx >> 3, c = idx & 7;
            const int kc = (c ^ (row & 7)) << 3;
            ld_g2l(&A[(size_t)(m0 + row) * K + k0 + kc], &As[idx << 3]);
        }
#pragma unroll
        for (int i = 0; i < 4; i++) {
            const int idx = i * 256 + tid;
            const int row = idx >> 3, c = idx & 7;
            const int kc = (c ^ (row & 7)) << 3;
            ld_g2l(&Bt[(size_t)(n0 + row) * K + k0 + kc], &Bs[idx << 3]);
        }
        __syncthreads();
#pragma unroll
        for (int ks = 0; ks < 2; ks++) {
            bf16x8 af[MT], bfr[4];
            const int pc = (((ks << 2) | quad) ^ (cc & 7)) << 3;
#pragma unroll
            for (int t = 0; t < MT; t++)
                af[t]  = *(const bf16x8*)&As[(wm + t * 16 + cc) * 64 + pc];
#pragma unroll
            for (int t = 0; t < 4; t++)
                bfr[t] = *(const bf16x8*)&Bs[(wn + t * 16 + cc) * 64 + pc];
#pragma unroll
            for (int mt = 0; mt < MT; mt++)
#pragma unroll
                for (int nt = 0; nt < 4; nt++)
                    acc[mt][nt] = __builtin_amdgcn_mfma_f32_16x16x32_bf16(
                        af[mt], bfr[nt], acc[mt][nt], 0, 0, 0);
        }
    }

    // ---- epilogues. C-frag: row = quad*4+r, col = cc ----
    if (EPI == EPI_GB) {
        unsigned short* C = (unsigned short*)Cv;
#pragma unroll
        for (int mt = 0; mt < MT; mt++)
#pragma unroll
        for (int r = 0; r < 4; r++) {
            const int m = m0 + wm + mt * 16 + quad * 4 + r;
#pragma unroll
            for (int nt = 0; nt < 4; nt++) {
                const int n = n0 + wn + nt * 16 + cc;
                const float b = (n < 2048) ? bias[n] : bias2[n - 2048];
                C[(size_t)m * 4096 + n] = f2bf(acc[mt][nt][r] + b);
            }
        }
    } else if (EPI == EPI_PROJ) {
        float* C = (float*)Cv;
#pragma unroll
        for (int mt = 0; mt < MT; mt++)
#pragma unroll
        for (int r = 0; r < 4; r++) {
            const int m = m0 + wm + mt * 16 + quad * 4 + r;
#pragma unroll
            for (int nt = 0; nt < 4; nt++) {
                const int n = n0 + wn + nt * 16 + cc;
                C[(size_t)m * 1024 + n] = acc[mt][nt][r] + res[(size_t)m * 1024 + n];
            }
        }
    } else if (EPI == EPI_FFN1) {
        unsigned short* C = (unsigned short*)Cv;
#pragma unroll
        for (int mt = 0; mt < MT; mt++)
#pragma unroll
        for (int r = 0; r < 4; r++) {
            const int m = m0 + wm + mt * 16 + quad * 4 + r;
#pragma unroll
            for (int nt = 0; nt < 4; nt++) {
                const int n = n0 + wn + nt * 16 + cc;
                float v = acc[mt][nt][r] + bias[n];
                // tanh-approx GELU: x / (1 + exp2(-2.3022084*(x + 0.044715 x^3)))
                const float u = v + 0.044715f * v * v * v;
                const float g = v / (1.f + exp2f(-2.3022084f * u));
                C[(size_t)m * 4096 + n] = f2bf(g);
            }
        }
    } else if (EPI == EPI_FFN2) {
        float* C = (float*)Cv;
#pragma unroll
        for (int mt = 0; mt < MT; mt++)
#pragma unroll
        for (int r = 0; r < 4; r++) {
            const int m = m0 + wm + mt * 16 + quad * 4 + r;
#pragma unroll
            for (int nt = 0; nt < 4; nt++) {
                const int n = n0 + wn + nt * 16 + cc;
                C[(size_t)m * 1024 + n] = acc[mt][nt][r] + bias[n] + res[(size_t)m * 1024 + n];
            }
        }
    } else {  // EPI_QKV: N=3072, split q/k bf16 + PERMUTED v^T bf16
        const int region = n0 >> 10;
        const int b = m0 >> 11;
        if (region < 2) {
            unsigned short* dst = region ? kb : qb;
            // Q prescale folds softmax 1/sqrt(d) AND log2(e)
            const float sc = region ? 1.0f : 0.125f * 1.44269504088896340736f;
#pragma unroll
            for (int mt = 0; mt < MT; mt++)
#pragma unroll
            for (int r = 0; r < 4; r++) {
                const int m = m0 + wm + mt * 16 + quad * 4 + r;
                const int s = m & 2047;
#pragma unroll
                for (int nt = 0; nt < 4; nt++) {
                    const int n = (n0 + wn + nt * 16 + cc) & 1023;
                    const int hh = n >> 6, d = n & 63;
                    dst[(((size_t)b * 16 + hh) * 2048 + s) * 64 + d] =
                        f2bf(acc[mt][nt][r] * sc);
                }
            }
        } else {
            // V^T stored pre-permuted into PV B-fragment key order
            const int sb = (m0 + wm) & 2047;
#pragma unroll
            for (int mt = 0; mt < MT; mt++) {
                const int kpos = sb + ((mt >> 1) << 5) + (quad << 3) + ((mt & 1) << 2);
#pragma unroll
                for (int nt = 0; nt < 4; nt++) {
                    const int n = (n0 + wn + nt * 16 + cc) & 1023;
                    const int hh = n >> 6, d = n & 63;
                    ushort4 o;
                    o.x = f2bf(acc[mt][nt][0]); o.y = f2bf(acc[mt][nt][1]);
                    o.z = f2bf(acc[mt][nt][2]); o.w = f2bf(acc[mt][nt][3]);
                    *(ushort4*)&vtb[(((size_t)b * 16 + hh) * 64 + d) * 2048 + kpos] = o;
                }
            }
        }
    }
}

// ---------------------------------------------------------------------------
// Transposed MFMA flash attention (v4 structure, zero-conflict), split-K x4:
// z in {0,1,2,3}, 512 keys each. 8 waves x 32 q = 256-q tile.
// grid (SEQ/256, B*H, 4) = 1024 blocks -> 4 blocks/CU = 32 waves/CU.
// Static-max exp2 softmax; partial O (bf16, unscaled) + partial l out.
// ---------------------------------------------------------------------------
__global__ __launch_bounds__(512) void attn_mfma(
    const unsigned short* __restrict__ qb, const unsigned short* __restrict__ kb,
    const unsigned short* __restrict__ vtb,
    unsigned short* __restrict__ Op0, unsigned short* __restrict__ Op1,
    unsigned short* __restrict__ Op2, unsigned short* __restrict__ Op3,
    float* __restrict__ lp)
{
    __shared__ __align__(16) unsigned short ks[64 * 64];   // [key][d] swizzled
    __shared__ __align__(16) unsigned short vts[64 * 64];  // [d][pos] swizzled

    const int tid = threadIdx.x;
    const int lane = tid & 63, w = tid >> 6;           // 8 waves
    const int c = lane & 15, quad = lane >> 4;
    const int bh = blockIdx.y;
    const int q0 = blockIdx.x * 256;
    const int z = blockIdx.z;
    const int kk0 = z * 512;

    // Q as B-operand: lane needs Q[q0+w*32+qs*16+c][kh*32+quad*8+j]
    bf16x8 qf[2][2];   // [qs][kh]
#pragma unroll
    for (int qs = 0; qs < 2; qs++) {
        const size_t base = (((size_t)bh * 2048) + q0 + w * 32 + qs * 16 + c) * 64 + quad * 8;
        qf[qs][0] = *(const bf16x8*)&qb[base];
        qf[qs][1] = *(const bf16x8*)&qb[base + 32];
    }

    f32x4 of[2][4];
#pragma unroll
    for (int qs = 0; qs < 2; qs++)
#pragma unroll
        for (int i = 0; i < 4; i++) of[qs][i] = (f32x4)0.f;
    float l[2] = {0.f, 0.f};

    const size_t kbase = ((size_t)bh * 2048) * 64;
    const size_t vbase = ((size_t)bh * 64) * 2048;

    // stage addressing: 512 chunks of 16B per tile, one per thread
    const int srow = tid >> 3, spc = tid & 7;
    const int slc = spc ^ (srow & 7);

    for (int kk = kk0; kk < kk0 + 512; kk += 64) {
        __syncthreads();
        ld_g2l(&kb[kbase + (size_t)(kk + srow) * 64 + slc * 8], &ks[tid << 3]);
        ld_g2l(&vtb[vbase + (size_t)srow * 2048 + kk + slc * 8], &vts[tid << 3]);
        __syncthreads();

        // ---- S^T = K @ Q^T ----
        f32x4 sc[2][4];
#pragma unroll
        for (int qs = 0; qs < 2; qs++)
#pragma unroll
            for (int t = 0; t < 4; t++) sc[qs][t] = (f32x4)0.f;
#pragma unroll
        for (int t = 0; t < 4; t++) {
#pragma unroll
            for (int kh = 0; kh < 2; kh++) {
                const int phys = ((kh * 4 + quad) ^ (c & 7)) << 3;
                bf16x8 kf = *(const bf16x8*)&ks[(t * 16 + c) * 64 + phys];
#pragma unroll
                for (int qs = 0; qs < 2; qs++)
                    sc[qs][t] = __builtin_amdgcn_mfma_f32_16x16x32_bf16(
                        kf, qf[qs][kh], sc[qs][t], 0, 0, 0);
            }
        }

        // ---- softmax: static max, exp2 domain, lane-local l ----
        bf16x8 pb[2][2];
#pragma unroll
        for (int qs = 0; qs < 2; qs++) {
#pragma unroll
            for (int t = 0; t < 4; t++)
#pragma unroll
                for (int r = 0; r < 4; r++) {
                    const float p = exp2f(sc[qs][t][r]);
                    sc[qs][t][r] = p;
                    l[qs] += p;
                }
#pragma unroll
            for (int kh = 0; kh < 2; kh++) {
                union { int4 i; bf16x8 v; } u;
                u.i.x = pk2bf(sc[qs][2 * kh][0],     sc[qs][2 * kh][1]);
                u.i.y = pk2bf(sc[qs][2 * kh][2],     sc[qs][2 * kh][3]);
                u.i.z = pk2bf(sc[qs][2 * kh + 1][0], sc[qs][2 * kh + 1][1]);
                u.i.w = pk2bf(sc[qs][2 * kh + 1][2], sc[qs][2 * kh + 1][3]);
                pb[qs][kh] = u.v;
            }
        }

        // ---- O^T += V^T @ P^T ----
#pragma unroll
        for (int dt = 0; dt < 4; dt++) {
#pragma unroll
            for (int kh = 0; kh < 2; kh++) {
                const int phys = ((kh * 4 + quad) ^ (c & 7)) << 3;
                bf16x8 vf = *(const bf16x8*)&vts[(dt * 16 + c) * 64 + phys];
#pragma unroll
                for (int qs = 0; qs < 2; qs++)
                    of[qs][dt] = __builtin_amdgcn_mfma_f32_16x16x32_bf16(
                        vf, pb[qs][kh], of[qs][dt], 0, 0, 0);
            }
        }
    }

    // ---- epilogue: store UNSCALED partial O (bf16) + partial l ----
    unsigned short* Op = (z == 0) ? Op0 : (z == 1) ? Op1 : (z == 2) ? Op2 : Op3;
    const int b = bh >> 4, hh = bh & 15;
#pragma unroll
    for (int qs = 0; qs < 2; qs++) {
        float lq = l[qs];
        lq += __shfl_xor(lq, 16, 64);
        lq += __shfl_xor(lq, 32, 64);
        const int q = q0 + w * 32 + qs * 16 + c;
        if (lane < 16)
            lp[((size_t)z * 32 + bh) * 2048 + q] = lq;
        const size_t row = (size_t)(b * 2048 + q);
#pragma unroll
        for (int dt = 0; dt < 4; dt++) {
            ushort4 o;
            o.x = f2bf(of[qs][dt][0]); o.y = f2bf(of[qs][dt][1]);
            o.z = f2bf(of[qs][dt][2]); o.w = f2bf(of[qs][dt][3]);
            *(ushort4*)&Op[row * 1024 + hh * 64 + dt * 16 + quad * 4] = o;
        }
    }
}

// ---------------------------------------------------------------------------
// merge_attn: attnb = (Op0+Op1+Op2+Op3) / (l0+l1+l2+l3), bf16 out.
// ---------------------------------------------------------------------------
__global__ __launch_bounds__(256) void merge_attn(
    const unsigned short* __restrict__ Op0, const unsigned short* __restrict__ Op1,
    const unsigned short* __restrict__ Op2, const unsigned short* __restrict__ Op3,
    const float* __restrict__ lp, unsigned short* __restrict__ attnb)
{
    const int row = blockIdx.x;
    const int b = row >> 11, s = row & 2047;
    const int tid = threadIdx.x;
    const int n = tid * 4, h = tid >> 4;
    float lsum = 0.f;
#pragma unroll
    for (int z = 0; z < 4; z++)
        lsum += lp[((size_t)z * 32 + b * 16 + h) * 2048 + s];
    const float inv = 1.f / lsum;
    const size_t off = (size_t)row * 1024 + n;
    ushort4 a0 = *(const ushort4*)&Op0[off];
    ushort4 a1 = *(const ushort4*)&Op1[off];
    ushort4 a2 = *(const ushort4*)&Op2[off];
    ushort4 a3 = *(const ushort4*)&Op3[off];
    ushort4 o;
    o.x = f2bf((bf2f(a0.x) + bf2f(a1.x) + bf2f(a2.x) + bf2f(a3.x)) * inv);
    o.y = f2bf((bf2f(a0.y) + bf2f(a1.y) + bf2f(a2.y) + bf2f(a3.y)) * inv);
    o.z = f2bf((bf2f(a0.z) + bf2f(a1.z) + bf2f(a2.z) + bf2f(a3.z)) * inv);
    o.w = f2bf((bf2f(a0.w) + bf2f(a1.w) + bf2f(a2.w) + bf2f(a3.w)) * inv);
    *(ushort4*)&attnb[off] = o;
}

// ---------------------------------------------------------------------------
// AdaLN (vectorized): x fp32, gamma/beta bf16 (stride 4096, +gboff), out bf16
// ---------------------------------------------------------------------------
__global__ __launch_bounds__(256) void adaln_bf(
    const float* __restrict__ x, const unsigned short* __restrict__ gb, int gboff,
    unsigned short* __restrict__ h)
{
    const int row = blockIdx.x;
    const float* xr = x + (size_t)row * D_MODEL;
    float4 v = ((const float4*)xr)[threadIdx.x];
    float s = v.x + v.y + v.z + v.w;
    float ss = v.x * v.x + v.y * v.y + v.z * v.z + v.w * v.w;
#pragma unroll
    for (int off = 1; off < 64; off <<= 1) {
        s  += __shfl_xor(s, off, 64);
        ss += __shfl_xor(ss, off, 64);
    }
    __shared__ float red[8];
    const int wave = threadIdx.x >> 6;
    if ((threadIdx.x & 63) == 0) { red[wave] = s; red[4 + wave] = ss; }
    __syncthreads();
    s  = red[0] + red[1] + red[2] + red[3];
    ss = red[4] + red[5] + red[6] + red[7];
    const float mu = s * (1.f / 1024.f);
    const float var = ss * (1.f / 1024.f) - mu * mu;
    const float rstd = rsqrtf(var + 1e-5f);
    const int c = threadIdx.x * 4;
    ushort4 g4 = *(const ushort4*)&gb[(size_t)row * 4096 + gboff + c];
    ushort4 b4 = *(const ushort4*)&gb[(size_t)row * 4096 + gboff + 1024 + c];
    ushort4 o;
    o.x = f2bf((v.x - mu) * rstd * (1.f + bf2f(g4.x)) + bf2f(b4.x));
    o.y = f2bf((v.y - mu) * rstd * (1.f + bf2f(g4.y)) + bf2f(b4.y));
    o.z = f2bf((v.z - mu) * rstd * (1.f + bf2f(g4.z)) + bf2f(b4.z));
    o.w = f2bf((v.w - mu) * rstd * (1.f + bf2f(g4.w)) + bf2f(b4.w));
    *(ushort4*)&h[(size_t)row * 1024 + c] = o;
}

// ---------------------------------------------------------------------------
extern "C" void kernel_launch(void* const* d_in, const int* in_sizes, int n_in,
                              void* d_out, int out_size, void* d_ws, size_t ws_size,
                              hipStream_t stream)
{
    const float* x      = (const float*)d_in[0];
    const float* cond   = (const float*)d_in[1];
    const float* p1_w   = (const float*)d_in[2];
    const float* p1_b   = (const float*)d_in[3];
    const float* qkv_w  = (const float*)d_in[4];
    const float* attn_w = (const float*)d_in[5];
    const float* p2_w   = (const float*)d_in[6];
    const float* p2_b   = (const float*)d_in[7];
    const float* ffn_w1 = (const float*)d_in[8];
    const float* ffn_b1 = (const float*)d_in[9];
    const float* ffn_w2 = (const float*)d_in[10];
    const float* ffn_b2 = (const float*)d_in[11];
    float* out = (float*)d_out;

    char* ws = (char*)d_ws;
    const size_t MB = 1024ull * 1024ull;
    unsigned short* wt_cond = (unsigned short*)(ws);             // [0,4)   dead after GB
    unsigned short* wt_qkv  = (unsigned short*)(ws + 4 * MB);    // [4,10)  dead after QKV
    unsigned short* wt_attn = (unsigned short*)(ws + 10 * MB);   // [10,12)
    unsigned short* wt_ffn1 = (unsigned short*)(ws + 12 * MB);   // [12,20)
    unsigned short* wt_ffn2 = (unsigned short*)(ws + 20 * MB);   // [20,28)
    unsigned short* siluc   = (unsigned short*)(ws + 28 * MB);   // [28,32) dead after GB
    unsigned short* gb      = (unsigned short*)(ws + 32 * MB);   // [32,64)
    unsigned short* h       = (unsigned short*)(ws + 64 * MB);   // [64,72) h1 dead after QKV
    float*          x1      = (float*)(ws + 72 * MB);            // [72,88) written by PROJ
    unsigned short* qb      = (unsigned short*)(ws + 88 * MB);   // [88,96)
    unsigned short* kb      = (unsigned short*)(ws + 96 * MB);   // [96,104)
    unsigned short* vtb     = (unsigned short*)(ws + 104 * MB);  // [104,112)
    unsigned short* attnb   = (unsigned short*)(ws + 112 * MB);  // [112,120)
    unsigned short* ff1     = (unsigned short*)(ws + 88 * MB);   // [88,120) overlay
    // attention partials, overlaying regions dead at attention time:
    unsigned short* Op0     = (unsigned short*)(ws);             // [0,8)   wt_cond+wt_qkv dead
    unsigned short* Op1     = (unsigned short*)(ws + 64 * MB);   // [64,72) h1 dead
    unsigned short* Op2     = (unsigned short*)(ws + 72 * MB);   // [72,80) x1 written later
    unsigned short* Op3     = (unsigned short*)(ws + 80 * MB);   // [80,88) x1 written later
    float*          lp      = (float*)(ws + 28 * MB);            // [28,29) siluc dead, 1MB

    dim3 blk(256);

    // one dispatch: all weight transposes + silu(cond)
    prep_weights<<<dim3(4096), blk, 0, stream>>>(
        p1_w, p2_w, qkv_w, attn_w, ffn_w1, ffn_w2, cond,
        wt_cond, wt_qkv, wt_attn, wt_ffn1, wt_ffn2, siluc);

    // gb = silu(cond) @ [p1_w|p2_w] + [p1_b|p2_b]   (4096x4096, K=512)
    gemm_bf16<EPI_GB, 128><<<dim3(32, 32), blk, 0, stream>>>(
        siluc, wt_cond, p1_b, p2_b, nullptr, gb, nullptr, nullptr, nullptr, 512);
    // h1 = adaln(x, gb1)
    adaln_bf<<<NTOK, blk, 0, stream>>>(x, gb, 0, h);
    // qkv = h1 @ qkv_w  -> q/k bf16 (Q prescaled), v^T bf16 pre-permuted
    gemm_bf16<EPI_QKV, 128><<<dim3(24, 32), blk, 0, stream>>>(
        h, wt_qkv, nullptr, nullptr, nullptr, nullptr, qb, kb, vtb, 1024);
    // attention: split-K x4, 8-wave blocks -> 1024 blocks (4/CU, 32 waves/CU)
    attn_mfma<<<dim3(SEQ / 256, 32, 4), dim3(512), 0, stream>>>(
        qb, kb, vtb, Op0, Op1, Op2, Op3, lp);
    merge_attn<<<dim3(NTOK), blk, 0, stream>>>(Op0, Op1, Op2, Op3, lp, attnb);
    // x1 = x + attn @ attn_out_w   (BM=64 -> 512 blocks)
    gemm_bf16<EPI_PROJ, 64><<<dim3(8, 64), blk, 0, stream>>>(
        attnb, wt_attn, nullptr, nullptr, x, x1, nullptr, nullptr, nullptr, 1024);
    // h2 = adaln(x1, gb2)
    adaln_bf<<<NTOK, blk, 0, stream>>>(x1, gb, 2048, h);
    // ff1 = gelu_tanh(h2 @ ffn_w1 + b1)
    gemm_bf16<EPI_FFN1, 128><<<dim3(32, 32), blk, 0, stream>>>(
        h, wt_ffn1, ffn_b1, nullptr, nullptr, ff1, nullptr, nullptr, nullptr, 1024);
    // out = x1 + ff1 @ ffn_w2 + b2   (BM=64 -> 512 blocks)
    gemm_bf16<EPI_FFN2, 64><<<dim3(8, 64), blk, 0, stream>>>(
        ff1, wt_ffn2, ffn_b2, nullptr, x1, out, nullptr, nullptr, nullptr, 4096);
}